// Round 1
// baseline (356.185 us; speedup 1.0000x reference)
//
#include <hip/hip_runtime.h>
#include <math.h>

typedef short v8s __attribute__((ext_vector_type(8)));
typedef short v4s __attribute__((ext_vector_type(4)));
typedef float v4f __attribute__((ext_vector_type(4)));
typedef unsigned long long ull;

constexpr int L_ = 2048;
constexpr int H_ = 2048;
constexpr float LOG2E = 1.4426950408889634f;
constexpr float QSCALE = 0.08838834764831845f * LOG2E; // 1/sqrt(128) * log2(e)

__device__ inline unsigned short f2bf(float f) {
    unsigned int u = __float_as_uint(f);
    u += 0x7fffu + ((u >> 16) & 1u);
    return (unsigned short)(u >> 16);
}

// pack two fp32 -> two bf16 in one u32 (round-half-up): 2 adds + 1 v_perm
__device__ inline unsigned int pk2bf(float lo, float hi) {
    unsigned int a = __float_as_uint(lo) + 0x8000u;
    unsigned int b = __float_as_uint(hi) + 0x8000u;
    return __builtin_amdgcn_perm(b, a, 0x07060302);  // {hi16(b), hi16(a)}
}

// async global->LDS, 16 bytes per lane; LDS dest = uniform base + lane*16B
__device__ inline void async16(const void* g, void* l) {
    __builtin_amdgcn_global_load_lds(
        (const __attribute__((address_space(1))) unsigned int*)g,
        (__attribute__((address_space(3))) unsigned int*)l, 16, 0, 0);
}

// ---------------------------------------------------------------------------
// Fused conversion kernel: x, Wq, Wk(->wqkv+2048*2048), Wv(->wqkv+2560*2048),
// Wo -> bf16; mask -> mask*log2e (fp32).
// ---------------------------------------------------------------------------
__global__ __launch_bounds__(256) void conv_all(
    const float* __restrict__ x,  const float* __restrict__ wq,
    const float* __restrict__ wk, const float* __restrict__ wv,
    const float* __restrict__ wo, const float* __restrict__ mask,
    unsigned short* __restrict__ xb, unsigned short* __restrict__ wqkvb,
    unsigned short* __restrict__ wob, float* __restrict__ maskL)
{
    int u = blockIdx.x * 256 + threadIdx.x;
    const float* s;
    unsigned short* d;
    if (u < 1048576)      { s = x  + (size_t)u * 8;             d = xb   + (size_t)u * 8; }
    else if (u < 1572864) { size_t t = (size_t)(u - 1048576) * 8; s = wq + t; d = wqkvb + t; }
    else if (u < 1703936) { size_t t = (size_t)(u - 1572864) * 8; s = wk + t; d = wqkvb + (size_t)2048 * 2048 + t; }
    else if (u < 1835008) { size_t t = (size_t)(u - 1703936) * 8; s = wv + t; d = wqkvb + (size_t)2560 * 2048 + t; }
    else if (u < 2359296) { size_t t = (size_t)(u - 1835008) * 8; s = wo + t; d = wob + t; }
    else if (u < 2359808) {
        int m = (u - 2359296) * 8;
        float4 a = *(const float4*)(mask + m);
        float4 b = *(const float4*)(mask + m + 4);
        float4 oa = {a.x * LOG2E, a.y * LOG2E, a.z * LOG2E, a.w * LOG2E};
        float4 ob = {b.x * LOG2E, b.y * LOG2E, b.z * LOG2E, b.w * LOG2E};
        *(float4*)(maskL + m) = oa;
        *(float4*)(maskL + m + 4) = ob;
        return;
    } else return;
    float4 a = *(const float4*)s;
    float4 b = *(const float4*)(s + 4);
    v8s o;
    o[0] = (short)f2bf(a.x); o[1] = (short)f2bf(a.y);
    o[2] = (short)f2bf(a.z); o[3] = (short)f2bf(a.w);
    o[4] = (short)f2bf(b.x); o[5] = (short)f2bf(b.y);
    o[6] = (short)f2bf(b.z); o[7] = (short)f2bf(b.w);
    *(v8s*)d = o;
}

// ---------------------------------------------------------------------------
// bf16 MFMA GEMM, triple-buffered async staging (prefetch distance 2,
// ONE barrier per K-iter). 128x128x32 tiles, 4 waves, 64x64/wave.
// MODE 0: fp32 out + bias + residual (O-proj).
// MODE 3: fused QKV; cols [0,2048) Q (scaled), [2048,2560) K, [2560,3072) V.
// ---------------------------------------------------------------------------
template <int MODE>
__global__ __launch_bounds__(256) void gemm_mfma(
    const unsigned short* __restrict__ A, const unsigned short* __restrict__ W,
    const float* __restrict__ b0, const float* __restrict__ b1,
    const float* __restrict__ b2,
    unsigned short* __restrict__ oq, unsigned short* __restrict__ ok,
    unsigned short* __restrict__ ov,
    float* __restrict__ of, const float* __restrict__ resid,
    int K, int N)
{
    __shared__ short SM[3 * 8192];   // per buf: A 4096 shorts | B 4096 shorts

    const int tid  = threadIdx.x;
    const int lane = tid & 63;
    const int wave = tid >> 6;
    const int lid  = lane & 15;
    const int g    = lane >> 4;
    const int wr   = wave >> 1, wc = wave & 1;
    const int row0 = blockIdx.y * 128, col0 = blockIdx.x * 128;

    auto stage = [&](int k0, int buf) {
#pragma unroll
        for (int i = 0; i < 2; ++i) {
            int idx = tid + i * 256;               // 0..511
            int r = idx >> 2, s = idx & 3;
            int c = s ^ ((r >> 1) & 3);
            async16(A + (size_t)(row0 + r) * K + k0 + c * 8,
                    &SM[buf * 8192 + idx * 8]);
            async16(W + (size_t)(col0 + r) * K + k0 + c * 8,
                    &SM[buf * 8192 + 4096 + idx * 8]);
        }
    };

    v4f acc[4][4];
#pragma unroll
    for (int i = 0; i < 4; ++i)
#pragma unroll
        for (int j = 0; j < 4; ++j) acc[i][j] = (v4f){0.f, 0.f, 0.f, 0.f};

    stage(0, 0);
    stage(32, 1);
    int p = 0;
    for (int k0 = 0; k0 < K; k0 += 32) {
        __syncthreads();
        if (k0 + 64 < K) {
            int nb = p + 2; if (nb >= 3) nb -= 3;
            stage(k0 + 64, nb);
        }
        const short* As = &SM[p * 8192];
        const short* Bs = &SM[p * 8192 + 4096];

        v8s af[4], bf[4];
#pragma unroll
        for (int t = 0; t < 4; ++t) {
            int ra = wr * 64 + t * 16 + lid;
            int rb = wc * 64 + t * 16 + lid;
            af[t] = *(const v8s*)&As[ra * 32 + ((g ^ ((ra >> 1) & 3)) * 8)];
            bf[t] = *(const v8s*)&Bs[rb * 32 + ((g ^ ((rb >> 1) & 3)) * 8)];
        }
#pragma unroll
        for (int mt = 0; mt < 4; ++mt)
#pragma unroll
            for (int nt = 0; nt < 4; ++nt)
                acc[mt][nt] = __builtin_amdgcn_mfma_f32_16x16x32_bf16(
                    af[mt], bf[nt], acc[mt][nt], 0, 0, 0);
        if (++p == 3) p = 0;
    }

    // epilogue: C/D layout col = lane&15, row = g*4 + reg
    const int crow = row0 + wr * 64, ccol = col0 + wc * 64;
    if (MODE == 0) {
#pragma unroll
        for (int mt = 0; mt < 4; ++mt)
#pragma unroll
            for (int nt = 0; nt < 4; ++nt) {
                int cc = ccol + nt * 16 + lid;
                float bb = b0[cc];
#pragma unroll
                for (int r = 0; r < 4; ++r) {
                    int rr = crow + mt * 16 + g * 4 + r;
                    of[(size_t)rr * N + cc] =
                        acc[mt][nt][r] + bb + resid[(size_t)rr * N + cc];
                }
            }
    } else {
        const int seg = (col0 < 2048) ? 0 : (col0 < 2560 ? 1 : 2);
#pragma unroll
        for (int mt = 0; mt < 4; ++mt)
#pragma unroll
            for (int nt = 0; nt < 4; ++nt) {
                int cc = ccol + nt * 16 + lid;
                if (seg == 0) {
                    float bb = b0[cc];
#pragma unroll
                    for (int r = 0; r < 4; ++r) {
                        int rr = crow + mt * 16 + g * 4 + r;
                        oq[(size_t)rr * 2048 + cc] =
                            f2bf((acc[mt][nt][r] + bb) * QSCALE);
                    }
                } else if (seg == 1) {
                    float bb = b1[cc - 2048];
#pragma unroll
                    for (int r = 0; r < 4; ++r) {
                        int rr = crow + mt * 16 + g * 4 + r;
                        ok[(size_t)rr * 512 + (cc - 2048)] =
                            f2bf(acc[mt][nt][r] + bb);
                    }
                } else {
                    float bb = b2[cc - 2560];
#pragma unroll
                    for (int r = 0; r < 4; ++r) {
                        int rr = crow + mt * 16 + g * 4 + r;
                        ov[(size_t)rr * 512 + (cc - 2560)] =
                            f2bf(acc[mt][nt][r] + bb);
                    }
                }
            }
    }
}

// ---------------------------------------------------------------------------
// V transpose: [4096][512] -> Vt[(b*512 + c)][2048], LDS-tiled 64x64.
// ---------------------------------------------------------------------------
__global__ __launch_bounds__(256) void transpose_v(
    const unsigned short* __restrict__ V, unsigned short* __restrict__ Vt)
{
    __shared__ unsigned short T[64][72];
    const int r0 = blockIdx.y * 64;
    const int c0 = blockIdx.x * 64;
    const int tid = threadIdx.x;
    const int r = tid >> 3, c8 = (tid & 7) * 8;
#pragma unroll
    for (int h = 0; h < 2; ++h) {
        v8s val = *(const v8s*)&V[(size_t)(r0 + h * 32 + r) * 512 + c0 + c8];
#pragma unroll
        for (int e = 0; e < 8; ++e) T[c8 + e][h * 32 + r] = (unsigned short)val[e];
    }
    __syncthreads();
#pragma unroll
    for (int h = 0; h < 2; ++h) {
        int idx = tid + h * 256;
        int ci = idx >> 3, ch = (idx & 7) * 8;
        v8s o = *(const v8s*)&T[ci][ch];
        int rr = r0 + ch;
        *(v8s*)&Vt[((size_t)((rr >> 11) * 512 + c0 + ci)) * 2048 + (rr & 2047)] = o;
    }
}

// ---------------------------------------------------------------------------
// MFMA flash attention v5 (GQA). Block = 256 threads (4 waves), 128 q-rows
// per block (32 q-rows/wave) -> grid (16,16,2)=512 -> 2 blocks/CU (two
// INDEPENDENT barrier groups per CU). 32-key tiles, double-buffered K/V via
// global_load_lds, ONE barrier/iter. Streaming softmax (mask-seeded MFMA
// accumulator, exp2, unnormalized O + row-sum l).
//
// KEY CHANGE vs v4: no P_s LDS round-trip. The PV MFMA's k-slot labeling is
// arbitrary as long as A and B agree, so each lane feeds its OWN exp2'd
// sacc values (packed via pk2bf) as the A-fragment, and the B-fragment reads
// the matching PERMUTED V rows: k-slot g*8+j <-> key {g*4+j (j<4),
// 16+g*4+j-4 (j>=4)} = two contiguous 4-key runs -> 2x ds_read_b64 per nt.
// 8B-run swizzle c ^ (((d>>1)&3)<<1) keeps both b64 reads bank-balanced
// (4-cyc minimum) and is async16-compatible (even XOR preserves 16B pairs).
// ---------------------------------------------------------------------------
__global__ __launch_bounds__(256) void flash_mfma(
    const unsigned short* __restrict__ Q,   // [B*L, 2048] bf16, pre-scaled
    const unsigned short* __restrict__ K,   // [B*L, 512]  bf16
    const unsigned short* __restrict__ Vt,  // [(b*512+kvh*128+d)][2048] bf16
    const float* __restrict__ maskL,        // [B,L] fp32, pre-multiplied log2e
    unsigned short* __restrict__ AO)        // [B*L, 2048] bf16
{
    __shared__ short K_s[2][32 * 128];      // [buf][32 keys][16 chunks of 8]
    __shared__ short V_s[2][128 * 32];      // [buf][128 d][8 runs of 4 keys]

    const int tid  = threadIdx.x;
    const int lane = tid & 63;
    const int wave = tid >> 6;              // 0..3
    const int lid  = lane & 15;
    const int g    = lane >> 4;
    const int h    = blockIdx.y;
    const int b    = blockIdx.z;
    const int kvh  = h >> 2;
    const int q0   = blockIdx.x * 128;
    const int wq   = wave * 32;

    // staging pointers (strength-reduced: advance per iteration).
    // 256 threads stage 512 16B-chunks each of K and V (2 per thread).
    const unsigned short* pK;
    const unsigned short* pV;
    {
        int kr = tid >> 4, ks = tid & 15;   // kr 0..15 (+16 via offset)
        pK = K + ((size_t)(b * L_ + kr)) * 512 + kvh * 128 +
             ((ks ^ (kr & 15)) * 8);
        int vd = tid >> 2, vs = tid & 3;    // vd 0..63 (+64 via offset)
        pV = Vt + ((size_t)(b * 512 + kvh * 128 + vd)) * 2048 +
             ((vs ^ ((vd >> 1) & 3)) * 8);
    }

    // Q fragments: B-operand, lane n=q (lid), k = g*8+j within 32-chunk kc
    v8s bq[2][4];
    {
        const size_t base = ((size_t)(b * L_ + q0 + wq + lid)) * 2048 + h * 128;
#pragma unroll
        for (int qt = 0; qt < 2; ++qt)
#pragma unroll
            for (int kc = 0; kc < 4; ++kc)
                bq[qt][kc] = *(const v8s*)(Q + base + (size_t)qt * 16 * 2048 +
                                           kc * 32 + g * 8);
    }

    v4f oacc[2][8];
#pragma unroll
    for (int mt = 0; mt < 2; ++mt)
#pragma unroll
        for (int nt = 0; nt < 8; ++nt) oacc[mt][nt] = (v4f){0.f, 0.f, 0.f, 0.f};
    float lsm[2] = {0.f, 0.f};

    // prologue stage into buf 0
    async16(pK,              &K_s[0][tid * 8]);
    async16(pK + 16 * 512,   &K_s[0][(tid + 256) * 8]);
    async16(pV,              &V_s[0][tid * 8]);
    async16(pV + 64 * 2048,  &V_s[0][(tid + 256) * 8]);

    for (int it = 0; it < 64; ++it) {
        const int p = it & 1;
        const int k0 = it * 32;
        __syncthreads();                    // drains buf[p]; guards buf[p^1]
        pK += 32 * 512;                     // next 32 keys
        pV += 32;
        if (it + 1 < 64) {
            short* dK = K_s[p ^ 1];
            short* dV = V_s[p ^ 1];
            async16(pK,              &dK[tid * 8]);
            async16(pK + 16 * 512,   &dK[(tid + 256) * 8]);
            async16(pV,              &dV[tid * 8]);
            async16(pV + 64 * 2048,  &dV[(tid + 256) * 8]);
        }
        const short* Ks = K_s[p];
        const short* Vs = V_s[p];

        // S^T = K x Q, accumulator seeded with mask (log2 domain):
        // D[k][q], lane q = qt*16+lid, k = kt*16 + g*4 + r
        v4f sacc[2][2];
#pragma unroll
        for (int kt = 0; kt < 2; ++kt) {
            float4 mk = *(const float4*)&maskL[b * L_ + k0 + kt * 16 + g * 4];
            v4f seed = {mk.x, mk.y, mk.z, mk.w};
            sacc[kt][0] = seed;
            sacc[kt][1] = seed;
        }
#pragma unroll
        for (int kc = 0; kc < 4; ++kc)
#pragma unroll
            for (int kt = 0; kt < 2; ++kt) {
                v8s ak = *(const v8s*)&Ks[(kt * 16 + lid) * 128 +
                                          (((kc * 4 + g) ^ lid) * 8)];
#pragma unroll
                for (int qt = 0; qt < 2; ++qt)
                    sacc[kt][qt] = __builtin_amdgcn_mfma_f32_16x16x32_bf16(
                        ak, bq[qt][kc], sacc[kt][qt], 0, 0, 0);
            }

        // p = exp2(s); accumulate unnormalized row-sums; pack A-fragments
        // IN REGISTERS: lane (lid,g) owns P[q=qt*16+lid] for keys
        // {g*4+r, 16+g*4+r} which is exactly k-slots g*8+{0..7} under sigma.
        v8s ap[2];
#pragma unroll
        for (int qt = 0; qt < 2; ++qt) {
            float e0 = __builtin_amdgcn_exp2f(sacc[0][qt][0]);
            float e1 = __builtin_amdgcn_exp2f(sacc[0][qt][1]);
            float e2 = __builtin_amdgcn_exp2f(sacc[0][qt][2]);
            float e3 = __builtin_amdgcn_exp2f(sacc[0][qt][3]);
            float f0 = __builtin_amdgcn_exp2f(sacc[1][qt][0]);
            float f1 = __builtin_amdgcn_exp2f(sacc[1][qt][1]);
            float f2 = __builtin_amdgcn_exp2f(sacc[1][qt][2]);
            float f3 = __builtin_amdgcn_exp2f(sacc[1][qt][3]);
            lsm[qt] += ((e0 + e1) + (e2 + e3)) + ((f0 + f1) + (f2 + f3));
            union { uint4 u; v8s v; } pa;
            pa.u.x = pk2bf(e0, e1);
            pa.u.y = pk2bf(e2, e3);
            pa.u.z = pk2bf(f0, f1);
            pa.u.w = pk2bf(f2, f3);
            ap[qt] = pa.v;
        }

        // P·V accumulate: B-fragment = permuted V rows, 2x b64 per nt.
        // k-slot g*8+j -> key run c1=g (keys g*4..+3) and c2=4+g (16+g*4..+3),
        // stored at LDS 8B-slot c ^ (((d>>1)&3)<<1).
#pragma unroll
        for (int nt = 0; nt < 8; ++nt) {
            const int dcol = nt * 16 + lid;
            const short* vrow = &Vs[dcol * 32];
            const int fsw = ((dcol >> 1) & 3) << 1;
            v4s vlo = *(const v4s*)&vrow[(g ^ fsw) * 4];
            v4s vhi = *(const v4s*)&vrow[((4 | g) ^ fsw) * 4];
            v8s bvf = __builtin_shufflevector(vlo, vhi, 0, 1, 2, 3, 4, 5, 6, 7);
#pragma unroll
            for (int mt = 0; mt < 2; ++mt)
                oacc[mt][nt] = __builtin_amdgcn_mfma_f32_16x16x32_bf16(
                    ap[mt], bvf, oacc[mt][nt], 0, 0, 0);
        }
    }

    // reduce l across the 4 lane-groups (same q-row), normalize, store
#pragma unroll
    for (int qt = 0; qt < 2; ++qt) {
        lsm[qt] += __shfl_xor(lsm[qt], 16);
        lsm[qt] += __shfl_xor(lsm[qt], 32);
    }
#pragma unroll
    for (int mt = 0; mt < 2; ++mt) {
        float linv[4];
#pragma unroll
        for (int r = 0; r < 4; ++r) linv[r] = 1.0f / __shfl(lsm[mt], g * 4 + r);
#pragma unroll
        for (int nt = 0; nt < 8; ++nt)
#pragma unroll
            for (int r = 0; r < 4; ++r) {
                size_t orow = (size_t)(b * L_ + q0 + wq + mt * 16 + g * 4 + r);
                AO[orow * 2048 + h * 128 + nt * 16 + lid] =
                    f2bf(oacc[mt][nt][r] * linv[r]);
            }
    }
}

// ---------------------------------------------------------------------------
// LayerNorm over rows of P (P = proj + bias + residual already).
// ---------------------------------------------------------------------------
__global__ __launch_bounds__(256) void ln_kernel(
    const float* __restrict__ P, const float* __restrict__ g,
    const float* __restrict__ bta, float* __restrict__ Out)
{
    const int row = blockIdx.x;
    const int tid = threadIdx.x;
    const float* p = P + (size_t)row * H_;

    float vals[8];
    float s = 0.f;
#pragma unroll
    for (int it = 0; it < 2; ++it) {
        int c = tid * 4 + it * 1024;
        float4 a = *(const float4*)&p[c];
        vals[it * 4 + 0] = a.x; vals[it * 4 + 1] = a.y;
        vals[it * 4 + 2] = a.z; vals[it * 4 + 3] = a.w;
        s += a.x + a.y + a.z + a.w;
    }
    __shared__ float red[4];
    float t = s;
#pragma unroll
    for (int off = 32; off > 0; off >>= 1) t += __shfl_xor(t, off);
    if ((tid & 63) == 0) red[tid >> 6] = t;
    __syncthreads();
    float mean = (red[0] + red[1] + red[2] + red[3]) * (1.f / (float)H_);

    float vsum = 0.f;
#pragma unroll
    for (int i = 0; i < 8; ++i) {
        float d = vals[i] - mean;
        vsum += d * d;
    }
    __syncthreads();
    t = vsum;
#pragma unroll
    for (int off = 32; off > 0; off >>= 1) t += __shfl_xor(t, off);
    if ((tid & 63) == 0) red[tid >> 6] = t;
    __syncthreads();
    float var = (red[0] + red[1] + red[2] + red[3]) * (1.f / (float)H_);
    float rs  = 1.f / sqrtf(var + 1e-12f);

#pragma unroll
    for (int it = 0; it < 2; ++it) {
        int c = tid * 4 + it * 1024;
        float4 gv = *(const float4*)&g[c];
        float4 bv = *(const float4*)&bta[c];
        float4 ov;
        ov.x = (vals[it * 4 + 0] - mean) * rs * gv.x + bv.x;
        ov.y = (vals[it * 4 + 1] - mean) * rs * gv.y + bv.y;
        ov.z = (vals[it * 4 + 2] - mean) * rs * gv.z + bv.z;
        ov.w = (vals[it * 4 + 3] - mean) * rs * gv.w + bv.w;
        *(float4*)&Out[(size_t)row * H_ + c] = ov;
    }
}

// ---------------------------------------------------------------------------
extern "C" void kernel_launch(void* const* d_in, const int* in_sizes, int n_in,
                              void* d_out, int out_size, void* d_ws, size_t ws_size,
                              hipStream_t stream)
{
    const float* x    = (const float*)d_in[0];
    const float* mask = (const float*)d_in[1];
    const float* Wq   = (const float*)d_in[2];
    const float* bq   = (const float*)d_in[3];
    const float* Wk   = (const float*)d_in[4];
    const float* bk   = (const float*)d_in[5];
    const float* Wv   = (const float*)d_in[6];
    const float* bv   = (const float*)d_in[7];
    const float* Wo   = (const float*)d_in[8];
    const float* bo   = (const float*)d_in[9];
    const float* lng  = (const float*)d_in[10];
    const float* lnb  = (const float*)d_in[11];
    float* out = (float*)d_out;

    char* ws = (char*)d_ws;
    unsigned short* xb    = (unsigned short*)(ws);              // 16.78 MB
    unsigned short* wqkv  = (unsigned short*)(ws + 16777216);   // 12.58 MB
    float*          maskL = (float*)         (ws + 29360128);   // 16 KB
    unsigned short* q     = (unsigned short*)(ws + 29376512);   // 16.78 MB
    unsigned short* k     = (unsigned short*)(ws + 46153728);   //  4.19 MB
    unsigned short* vnat  = (unsigned short*)(ws + 50348032);   //  4.19 MB
    unsigned short* vt    = (unsigned short*)(ws + 54542336);   //  4.19 MB
    unsigned short* ao    = (unsigned short*)(ws + 58736640);   // 16.78 MB
    unsigned short* wob   = (unsigned short*)(ws + 75513856);   //  8.39 MB
    float*          pj    = (float*)(ws);                       // 33.55 MB,
                                        // reuses xb/wqkv/maskL/q-head (dead)

    dim3 blk(256);
    // fused conversions (x, Wq, Wk, Wv, Wo, mask*log2e)
    conv_all<<<9218, blk, 0, stream>>>(x, Wq, Wk, Wv, Wo, mask,
                                       xb, wqkv, wob, maskL);

    // fused QKV projection (Q pre-scaled; V natural layout)
    gemm_mfma<3><<<dim3(24, 32), blk, 0, stream>>>(
        xb, wqkv, bq, bk, bv, q, k, vnat, nullptr, nullptr, 2048, 3072);

    // V transpose for flash
    transpose_v<<<dim3(8, 64), blk, 0, stream>>>(vnat, vt);

    // attention: 128 q-rows/block, 256 threads, grid 512 (2 blocks/CU)
    flash_mfma<<<dim3(16, 16, 2), dim3(256), 0, stream>>>(q, k, vt, maskL, ao);

    // output projection + bias + residual, then layernorm
    gemm_mfma<0><<<dim3(16, 32), blk, 0, stream>>>(
        ao, wob, bo, nullptr, nullptr, nullptr, nullptr, nullptr, pj, x, 2048, 2048);
    ln_kernel<<<4096, blk, 0, stream>>>(pj, lng, lnb, out);
}

// Round 2
// 353.380 us; speedup vs baseline: 1.0079x; 1.0079x over previous
//
#include <hip/hip_runtime.h>
#include <math.h>

typedef short v8s __attribute__((ext_vector_type(8)));
typedef short v4s __attribute__((ext_vector_type(4)));
typedef float v4f __attribute__((ext_vector_type(4)));
typedef unsigned long long ull;

constexpr int L_ = 2048;
constexpr int H_ = 2048;
constexpr float LOG2E = 1.4426950408889634f;
constexpr float QSCALE = 0.08838834764831845f * LOG2E; // 1/sqrt(128) * log2(e)

__device__ inline unsigned short f2bf(float f) {
    unsigned int u = __float_as_uint(f);
    u += 0x7fffu + ((u >> 16) & 1u);
    return (unsigned short)(u >> 16);
}

// pack two fp32 -> two bf16 in one u32 (round-half-up): 2 adds + 1 v_perm
__device__ inline unsigned int pk2bf(float lo, float hi) {
    unsigned int a = __float_as_uint(lo) + 0x8000u;
    unsigned int b = __float_as_uint(hi) + 0x8000u;
    return __builtin_amdgcn_perm(b, a, 0x07060302);  // {hi16(b), hi16(a)}
}

// async global->LDS, 16 bytes per lane; LDS dest = uniform base + lane*16B
__device__ inline void async16(const void* g, void* l) {
    __builtin_amdgcn_global_load_lds(
        (const __attribute__((address_space(1))) unsigned int*)g,
        (__attribute__((address_space(3))) unsigned int*)l, 16, 0, 0);
}

// ---------------------------------------------------------------------------
// Fused conversion kernel: x, Wq, Wk(->wqkv+2048*2048), Wv(->wqkv+2560*2048),
// Wo -> bf16; mask -> mask*log2e (fp32).
// ---------------------------------------------------------------------------
__global__ __launch_bounds__(256) void conv_all(
    const float* __restrict__ x,  const float* __restrict__ wq,
    const float* __restrict__ wk, const float* __restrict__ wv,
    const float* __restrict__ wo, const float* __restrict__ mask,
    unsigned short* __restrict__ xb, unsigned short* __restrict__ wqkvb,
    unsigned short* __restrict__ wob, float* __restrict__ maskL)
{
    int u = blockIdx.x * 256 + threadIdx.x;
    const float* s;
    unsigned short* d;
    if (u < 1048576)      { s = x  + (size_t)u * 8;             d = xb   + (size_t)u * 8; }
    else if (u < 1572864) { size_t t = (size_t)(u - 1048576) * 8; s = wq + t; d = wqkvb + t; }
    else if (u < 1703936) { size_t t = (size_t)(u - 1572864) * 8; s = wk + t; d = wqkvb + (size_t)2048 * 2048 + t; }
    else if (u < 1835008) { size_t t = (size_t)(u - 1703936) * 8; s = wv + t; d = wqkvb + (size_t)2560 * 2048 + t; }
    else if (u < 2359296) { size_t t = (size_t)(u - 1835008) * 8; s = wo + t; d = wob + t; }
    else if (u < 2359808) {
        int m = (u - 2359296) * 8;
        float4 a = *(const float4*)(mask + m);
        float4 b = *(const float4*)(mask + m + 4);
        float4 oa = {a.x * LOG2E, a.y * LOG2E, a.z * LOG2E, a.w * LOG2E};
        float4 ob = {b.x * LOG2E, b.y * LOG2E, b.z * LOG2E, b.w * LOG2E};
        *(float4*)(maskL + m) = oa;
        *(float4*)(maskL + m + 4) = ob;
        return;
    } else return;
    float4 a = *(const float4*)s;
    float4 b = *(const float4*)(s + 4);
    v8s o;
    o[0] = (short)f2bf(a.x); o[1] = (short)f2bf(a.y);
    o[2] = (short)f2bf(a.z); o[3] = (short)f2bf(a.w);
    o[4] = (short)f2bf(b.x); o[5] = (short)f2bf(b.y);
    o[6] = (short)f2bf(b.z); o[7] = (short)f2bf(b.w);
    *(v8s*)d = o;
}

// ---------------------------------------------------------------------------
// bf16 MFMA GEMM, triple-buffered async staging (prefetch distance 2,
// ONE barrier per K-iter). 128x128x32 tiles, 4 waves, 64x64/wave.
// MODE 0: fp32 out + bias + residual (O-proj).
// MODE 3: fused QKV; cols [0,2048) Q (scaled), [2048,2560) K, [2560,3072) V.
// ---------------------------------------------------------------------------
template <int MODE>
__global__ __launch_bounds__(256) void gemm_mfma(
    const unsigned short* __restrict__ A, const unsigned short* __restrict__ W,
    const float* __restrict__ b0, const float* __restrict__ b1,
    const float* __restrict__ b2,
    unsigned short* __restrict__ oq, unsigned short* __restrict__ ok,
    unsigned short* __restrict__ ov,
    float* __restrict__ of, const float* __restrict__ resid,
    int K, int N)
{
    __shared__ short SM[3 * 8192];   // per buf: A 4096 shorts | B 4096 shorts

    const int tid  = threadIdx.x;
    const int lane = tid & 63;
    const int wave = tid >> 6;
    const int lid  = lane & 15;
    const int g    = lane >> 4;
    const int wr   = wave >> 1, wc = wave & 1;
    const int row0 = blockIdx.y * 128, col0 = blockIdx.x * 128;

    auto stage = [&](int k0, int buf) {
#pragma unroll
        for (int i = 0; i < 2; ++i) {
            int idx = tid + i * 256;               // 0..511
            int r = idx >> 2, s = idx & 3;
            int c = s ^ ((r >> 1) & 3);
            async16(A + (size_t)(row0 + r) * K + k0 + c * 8,
                    &SM[buf * 8192 + idx * 8]);
            async16(W + (size_t)(col0 + r) * K + k0 + c * 8,
                    &SM[buf * 8192 + 4096 + idx * 8]);
        }
    };

    v4f acc[4][4];
#pragma unroll
    for (int i = 0; i < 4; ++i)
#pragma unroll
        for (int j = 0; j < 4; ++j) acc[i][j] = (v4f){0.f, 0.f, 0.f, 0.f};

    stage(0, 0);
    stage(32, 1);
    int p = 0;
    for (int k0 = 0; k0 < K; k0 += 32) {
        __syncthreads();
        if (k0 + 64 < K) {
            int nb = p + 2; if (nb >= 3) nb -= 3;
            stage(k0 + 64, nb);
        }
        const short* As = &SM[p * 8192];
        const short* Bs = &SM[p * 8192 + 4096];

        v8s af[4], bf[4];
#pragma unroll
        for (int t = 0; t < 4; ++t) {
            int ra = wr * 64 + t * 16 + lid;
            int rb = wc * 64 + t * 16 + lid;
            af[t] = *(const v8s*)&As[ra * 32 + ((g ^ ((ra >> 1) & 3)) * 8)];
            bf[t] = *(const v8s*)&Bs[rb * 32 + ((g ^ ((rb >> 1) & 3)) * 8)];
        }
#pragma unroll
        for (int mt = 0; mt < 4; ++mt)
#pragma unroll
            for (int nt = 0; nt < 4; ++nt)
                acc[mt][nt] = __builtin_amdgcn_mfma_f32_16x16x32_bf16(
                    af[mt], bf[nt], acc[mt][nt], 0, 0, 0);
        if (++p == 3) p = 0;
    }

    // epilogue: C/D layout col = lane&15, row = g*4 + reg
    const int crow = row0 + wr * 64, ccol = col0 + wc * 64;
    if (MODE == 0) {
#pragma unroll
        for (int mt = 0; mt < 4; ++mt)
#pragma unroll
            for (int nt = 0; nt < 4; ++nt) {
                int cc = ccol + nt * 16 + lid;
                float bb = b0[cc];
#pragma unroll
                for (int r = 0; r < 4; ++r) {
                    int rr = crow + mt * 16 + g * 4 + r;
                    of[(size_t)rr * N + cc] =
                        acc[mt][nt][r] + bb + resid[(size_t)rr * N + cc];
                }
            }
    } else {
        const int seg = (col0 < 2048) ? 0 : (col0 < 2560 ? 1 : 2);
#pragma unroll
        for (int mt = 0; mt < 4; ++mt)
#pragma unroll
            for (int nt = 0; nt < 4; ++nt) {
                int cc = ccol + nt * 16 + lid;
                if (seg == 0) {
                    float bb = b0[cc];
#pragma unroll
                    for (int r = 0; r < 4; ++r) {
                        int rr = crow + mt * 16 + g * 4 + r;
                        oq[(size_t)rr * 2048 + cc] =
                            f2bf((acc[mt][nt][r] + bb) * QSCALE);
                    }
                } else if (seg == 1) {
                    float bb = b1[cc - 2048];
#pragma unroll
                    for (int r = 0; r < 4; ++r) {
                        int rr = crow + mt * 16 + g * 4 + r;
                        ok[(size_t)rr * 512 + (cc - 2048)] =
                            f2bf(acc[mt][nt][r] + bb);
                    }
                } else {
                    float bb = b2[cc - 2560];
#pragma unroll
                    for (int r = 0; r < 4; ++r) {
                        int rr = crow + mt * 16 + g * 4 + r;
                        ov[(size_t)rr * 512 + (cc - 2560)] =
                            f2bf(acc[mt][nt][r] + bb);
                    }
                }
            }
    }
}

// ---------------------------------------------------------------------------
// V transpose: [4096][512] -> Vt[(b*512 + c)][2048], LDS-tiled 64x64.
// KEY CHANGE: columns of Vt are stored in PV k-slot order. Within each
// 32-key tile, position p = [g(2b)|hi(1b)|r(2b)] holds key [hi|g|r], i.e.
// pos g*8+hi*4+r <- key hi*16+g*4+r. Attention is order-independent over
// keys, so only V needs this (K/mask stay natural); it makes the flash PV
// B-fragment a single contiguous ds_read_b128.
// ---------------------------------------------------------------------------
__global__ __launch_bounds__(256) void transpose_v(
    const unsigned short* __restrict__ V, unsigned short* __restrict__ Vt)
{
    __shared__ unsigned short T[64][72];
    const int r0 = blockIdx.y * 64;
    const int c0 = blockIdx.x * 64;
    const int tid = threadIdx.x;
    const int r = tid >> 3, c8 = (tid & 7) * 8;
#pragma unroll
    for (int h = 0; h < 2; ++h) {
        v8s val = *(const v8s*)&V[(size_t)(r0 + h * 32 + r) * 512 + c0 + c8];
#pragma unroll
        for (int e = 0; e < 8; ++e) T[c8 + e][h * 32 + r] = (unsigned short)val[e];
    }
    __syncthreads();
#pragma unroll
    for (int h = 0; h < 2; ++h) {
        int idx = tid + h * 256;
        int ci = idx >> 3, ch = (idx & 7) * 8;   // ch = output pos base (mult of 8)
        int t32 = ch & 32;                        // which 32-key tile (0 or 32)
        int gg  = (ch >> 3) & 3;                  // g field of the 8-run
        int kb  = t32 + gg * 4;                   // keys kb..kb+3 and kb+16..+19
        uint2 lo = *(const uint2*)&T[ci][kb];
        uint2 hi = *(const uint2*)&T[ci][kb + 16];
        union { uint4 u; v8s v; } o;
        o.u.x = lo.x; o.u.y = lo.y; o.u.z = hi.x; o.u.w = hi.y;
        int rr = r0 + ch;
        *(v8s*)&Vt[((size_t)((rr >> 11) * 512 + c0 + ci)) * 2048 + (rr & 2047)] = o.v;
    }
}

// ---------------------------------------------------------------------------
// MFMA flash attention v6 (GQA). Block = 256 threads (4 waves), 128 q-rows
// per block (32 q-rows/wave) -> grid (16,16,2)=512 -> 2 blocks/CU (two
// INDEPENDENT barrier groups per CU). 32-key tiles, double-buffered K/V via
// global_load_lds, ONE barrier/iter. Streaming softmax (mask-seeded MFMA
// accumulator, exp2, unnormalized O + row-sum l).
//
// Register-direct P (no P_s LDS round-trip): lane (lid,g) owns P[q=lid] for
// keys {g*4+r, 16+g*4+r} = exactly A-fragment k-slots g*8+{0..7}. The V
// B-fragment is a SINGLE contiguous ds_read_b128 because Vt's columns are
// pre-permuted into k-slot order (see transpose_v), using v4's verified
// <=2-way-bank XOR swizzle (stage: vs ^ ((vd>>2)&3); read: (g^lh)*8).
// ---------------------------------------------------------------------------
__global__ __launch_bounds__(256) void flash_mfma(
    const unsigned short* __restrict__ Q,   // [B*L, 2048] bf16, pre-scaled
    const unsigned short* __restrict__ K,   // [B*L, 512]  bf16
    const unsigned short* __restrict__ Vt,  // [(b*512+kvh*128+d)][2048] bf16, k-slot order
    const float* __restrict__ maskL,        // [B,L] fp32, pre-multiplied log2e
    unsigned short* __restrict__ AO)        // [B*L, 2048] bf16
{
    __shared__ short K_s[2][32 * 128];      // [buf][32 keys][16 chunks of 8]
    __shared__ short V_s[2][128 * 32];      // [buf][128 d][4 chunks of 8 pos]

    const int tid  = threadIdx.x;
    const int lane = tid & 63;
    const int wave = tid >> 6;              // 0..3
    const int lid  = lane & 15;
    const int g    = lane >> 4;
    const int lh   = (lid >> 2) & 3;
    const int h    = blockIdx.y;
    const int b    = blockIdx.z;
    const int kvh  = h >> 2;
    const int q0   = blockIdx.x * 128;
    const int wq   = wave * 32;

    // staging pointers (strength-reduced: advance per iteration).
    // 256 threads stage 512 16B-chunks each of K and V (2 per thread).
    const unsigned short* pK;
    const unsigned short* pV;
    {
        int kr = tid >> 4, ks = tid & 15;   // kr 0..15 (+16 via offset)
        pK = K + ((size_t)(b * L_ + kr)) * 512 + kvh * 128 +
             ((ks ^ (kr & 15)) * 8);
        int vd = tid >> 2, vs = tid & 3;    // vd 0..63 (+64 via offset)
        pV = Vt + ((size_t)(b * 512 + kvh * 128 + vd)) * 2048 +
             ((vs ^ ((vd >> 2) & 3)) * 8);
    }

    // Q fragments: B-operand, lane n=q (lid), k = g*8+j within 32-chunk kc
    v8s bq[2][4];
    {
        const size_t base = ((size_t)(b * L_ + q0 + wq + lid)) * 2048 + h * 128;
#pragma unroll
        for (int qt = 0; qt < 2; ++qt)
#pragma unroll
            for (int kc = 0; kc < 4; ++kc)
                bq[qt][kc] = *(const v8s*)(Q + base + (size_t)qt * 16 * 2048 +
                                           kc * 32 + g * 8);
    }

    v4f oacc[2][8];
#pragma unroll
    for (int mt = 0; mt < 2; ++mt)
#pragma unroll
        for (int nt = 0; nt < 8; ++nt) oacc[mt][nt] = (v4f){0.f, 0.f, 0.f, 0.f};
    float lsm[2] = {0.f, 0.f};

    // prologue stage into buf 0
    async16(pK,              &K_s[0][tid * 8]);
    async16(pK + 16 * 512,   &K_s[0][(tid + 256) * 8]);
    async16(pV,              &V_s[0][tid * 8]);
    async16(pV + 64 * 2048,  &V_s[0][(tid + 256) * 8]);

    for (int it = 0; it < 64; ++it) {
        const int p = it & 1;
        const int k0 = it * 32;
        __syncthreads();                    // drains buf[p]; guards buf[p^1]
        pK += 32 * 512;                     // next 32 keys
        pV += 32;                           // next 32 positions (same tile order)
        if (it + 1 < 64) {
            short* dK = K_s[p ^ 1];
            short* dV = V_s[p ^ 1];
            async16(pK,              &dK[tid * 8]);
            async16(pK + 16 * 512,   &dK[(tid + 256) * 8]);
            async16(pV,              &dV[tid * 8]);
            async16(pV + 64 * 2048,  &dV[(tid + 256) * 8]);
        }
        const short* Ks = K_s[p];
        const short* Vs = V_s[p];

        // S^T = K x Q, accumulator seeded with mask (log2 domain):
        // D[k][q], lane q = qt*16+lid, k = kt*16 + g*4 + r
        v4f sacc[2][2];
#pragma unroll
        for (int kt = 0; kt < 2; ++kt) {
            float4 mk = *(const float4*)&maskL[b * L_ + k0 + kt * 16 + g * 4];
            v4f seed = {mk.x, mk.y, mk.z, mk.w};
            sacc[kt][0] = seed;
            sacc[kt][1] = seed;
        }
#pragma unroll
        for (int kc = 0; kc < 4; ++kc)
#pragma unroll
            for (int kt = 0; kt < 2; ++kt) {
                v8s ak = *(const v8s*)&Ks[(kt * 16 + lid) * 128 +
                                          (((kc * 4 + g) ^ lid) * 8)];
#pragma unroll
                for (int qt = 0; qt < 2; ++qt)
                    sacc[kt][qt] = __builtin_amdgcn_mfma_f32_16x16x32_bf16(
                        ak, bq[qt][kc], sacc[kt][qt], 0, 0, 0);
            }

        // p = exp2(s); accumulate unnormalized row-sums; pack A-fragments
        // IN REGISTERS: k-slot g*8+j holds key (j>>2)*16 + g*4 + (j&3).
        v8s ap[2];
#pragma unroll
        for (int qt = 0; qt < 2; ++qt) {
            float e0 = __builtin_amdgcn_exp2f(sacc[0][qt][0]);
            float e1 = __builtin_amdgcn_exp2f(sacc[0][qt][1]);
            float e2 = __builtin_amdgcn_exp2f(sacc[0][qt][2]);
            float e3 = __builtin_amdgcn_exp2f(sacc[0][qt][3]);
            float f0 = __builtin_amdgcn_exp2f(sacc[1][qt][0]);
            float f1 = __builtin_amdgcn_exp2f(sacc[1][qt][1]);
            float f2 = __builtin_amdgcn_exp2f(sacc[1][qt][2]);
            float f3 = __builtin_amdgcn_exp2f(sacc[1][qt][3]);
            lsm[qt] += ((e0 + e1) + (e2 + e3)) + ((f0 + f1) + (f2 + f3));
            union { uint4 u; v8s v; } pa;
            pa.u.x = pk2bf(e0, e1);
            pa.u.y = pk2bf(e2, e3);
            pa.u.z = pk2bf(f0, f1);
            pa.u.w = pk2bf(f2, f3);
            ap[qt] = pa.v;
        }

        // P·V accumulate: B-fragment = one contiguous b128 per nt
        // (Vs row d holds 32 positions in k-slot order, XOR-swizzled).
#pragma unroll
        for (int nt = 0; nt < 8; ++nt) {
            v8s bv = *(const v8s*)&Vs[(nt * 16 + lid) * 32 + ((g ^ lh) * 8)];
#pragma unroll
            for (int mt = 0; mt < 2; ++mt)
                oacc[mt][nt] = __builtin_amdgcn_mfma_f32_16x16x32_bf16(
                    ap[mt], bv, oacc[mt][nt], 0, 0, 0);
        }
    }

    // reduce l across the 4 lane-groups (same q-row), normalize, store
#pragma unroll
    for (int qt = 0; qt < 2; ++qt) {
        lsm[qt] += __shfl_xor(lsm[qt], 16);
        lsm[qt] += __shfl_xor(lsm[qt], 32);
    }
#pragma unroll
    for (int mt = 0; mt < 2; ++mt) {
        float linv[4];
#pragma unroll
        for (int r = 0; r < 4; ++r) linv[r] = 1.0f / __shfl(lsm[mt], g * 4 + r);
#pragma unroll
        for (int nt = 0; nt < 8; ++nt)
#pragma unroll
            for (int r = 0; r < 4; ++r) {
                size_t orow = (size_t)(b * L_ + q0 + wq + mt * 16 + g * 4 + r);
                AO[orow * 2048 + h * 128 + nt * 16 + lid] =
                    f2bf(oacc[mt][nt][r] * linv[r]);
            }
    }
}

// ---------------------------------------------------------------------------
// LayerNorm over rows of P (P = proj + bias + residual already).
// ---------------------------------------------------------------------------
__global__ __launch_bounds__(256) void ln_kernel(
    const float* __restrict__ P, const float* __restrict__ g,
    const float* __restrict__ bta, float* __restrict__ Out)
{
    const int row = blockIdx.x;
    const int tid = threadIdx.x;
    const float* p = P + (size_t)row * H_;

    float vals[8];
    float s = 0.f;
#pragma unroll
    for (int it = 0; it < 2; ++it) {
        int c = tid * 4 + it * 1024;
        float4 a = *(const float4*)&p[c];
        vals[it * 4 + 0] = a.x; vals[it * 4 + 1] = a.y;
        vals[it * 4 + 2] = a.z; vals[it * 4 + 3] = a.w;
        s += a.x + a.y + a.z + a.w;
    }
    __shared__ float red[4];
    float t = s;
#pragma unroll
    for (int off = 32; off > 0; off >>= 1) t += __shfl_xor(t, off);
    if ((tid & 63) == 0) red[tid >> 6] = t;
    __syncthreads();
    float mean = (red[0] + red[1] + red[2] + red[3]) * (1.f / (float)H_);

    float vsum = 0.f;
#pragma unroll
    for (int i = 0; i < 8; ++i) {
        float d = vals[i] - mean;
        vsum += d * d;
    }
    __syncthreads();
    t = vsum;
#pragma unroll
    for (int off = 32; off > 0; off >>= 1) t += __shfl_xor(t, off);
    if ((tid & 63) == 0) red[tid >> 6] = t;
    __syncthreads();
    float var = (red[0] + red[1] + red[2] + red[3]) * (1.f / (float)H_);
    float rs  = 1.f / sqrtf(var + 1e-12f);

#pragma unroll
    for (int it = 0; it < 2; ++it) {
        int c = tid * 4 + it * 1024;
        float4 gv = *(const float4*)&g[c];
        float4 bv = *(const float4*)&bta[c];
        float4 ov;
        ov.x = (vals[it * 4 + 0] - mean) * rs * gv.x + bv.x;
        ov.y = (vals[it * 4 + 1] - mean) * rs * gv.y + bv.y;
        ov.z = (vals[it * 4 + 2] - mean) * rs * gv.z + bv.z;
        ov.w = (vals[it * 4 + 3] - mean) * rs * gv.w + bv.w;
        *(float4*)&Out[(size_t)row * H_ + c] = ov;
    }
}

// ---------------------------------------------------------------------------
extern "C" void kernel_launch(void* const* d_in, const int* in_sizes, int n_in,
                              void* d_out, int out_size, void* d_ws, size_t ws_size,
                              hipStream_t stream)
{
    const float* x    = (const float*)d_in[0];
    const float* mask = (const float*)d_in[1];
    const float* Wq   = (const float*)d_in[2];
    const float* bq   = (const float*)d_in[3];
    const float* Wk   = (const float*)d_in[4];
    const float* bk   = (const float*)d_in[5];
    const float* Wv   = (const float*)d_in[6];
    const float* bv   = (const float*)d_in[7];
    const float* Wo   = (const float*)d_in[8];
    const float* bo   = (const float*)d_in[9];
    const float* lng  = (const float*)d_in[10];
    const float* lnb  = (const float*)d_in[11];
    float* out = (float*)d_out;

    char* ws = (char*)d_ws;
    unsigned short* xb    = (unsigned short*)(ws);              // 16.78 MB
    unsigned short* wqkv  = (unsigned short*)(ws + 16777216);   // 12.58 MB
    float*          maskL = (float*)         (ws + 29360128);   // 16 KB
    unsigned short* q     = (unsigned short*)(ws + 29376512);   // 16.78 MB
    unsigned short* k     = (unsigned short*)(ws + 46153728);   //  4.19 MB
    unsigned short* vnat  = (unsigned short*)(ws + 50348032);   //  4.19 MB
    unsigned short* vt    = (unsigned short*)(ws + 54542336);   //  4.19 MB
    unsigned short* ao    = (unsigned short*)(ws + 58736640);   // 16.78 MB
    unsigned short* wob   = (unsigned short*)(ws + 75513856);   //  8.39 MB
    float*          pj    = (float*)(ws);                       // 33.55 MB,
                                        // reuses xb/wqkv/maskL/q-head (dead)

    dim3 blk(256);
    // fused conversions (x, Wq, Wk, Wv, Wo, mask*log2e)
    conv_all<<<9218, blk, 0, stream>>>(x, Wq, Wk, Wv, Wo, mask,
                                       xb, wqkv, wob, maskL);

    // fused QKV projection (Q pre-scaled; V natural layout)
    gemm_mfma<3><<<dim3(24, 32), blk, 0, stream>>>(
        xb, wqkv, bq, bk, bv, q, k, vnat, nullptr, nullptr, 2048, 3072);

    // V transpose (k-slot-permuted columns) for flash
    transpose_v<<<dim3(8, 64), blk, 0, stream>>>(vnat, vt);

    // attention: 128 q-rows/block, 256 threads, grid 512 (2 blocks/CU)
    flash_mfma<<<dim3(16, 16, 2), dim3(256), 0, stream>>>(q, k, vt, maskL, ao);

    // output projection + bias + residual, then layernorm
    gemm_mfma<0><<<dim3(16, 32), blk, 0, stream>>>(
        ao, wob, bo, nullptr, nullptr, nullptr, nullptr, nullptr, pj, x, 2048, 2048);
    ln_kernel<<<4096, blk, 0, stream>>>(pj, lng, lnb, out);
}